// Round 7
// baseline (357.325 us; speedup 1.0000x reference)
//
#include <hip/hip_runtime.h>

// ---------------------------------------------------------------------------
// DirSageConv, bf16-MFMA + fp8-gather version.
//   Ab[N][384] bf16 = [ x | 0.5*mean_in(x) | 0.5*mean_out(x) ]
//   xq[N][128] fp8  = e4m3(x)                (gather payload, half bytes)
//   out[N][128] f32 = Ab @ Wt_cat^T + (b_self + 0.5*(b_s2d + b_d2s))
// Combined CSR over 2N node-dir space (idx = dir*N + node), one scan chain.
// fill is XCD-partitioned; R7: all one-pass streams use non-temporal loads
// so L2 keeps scatter-write lines (fill/deg) and gather lines (agg) resident.
// N=100000, E=800000, D=128.
// ---------------------------------------------------------------------------

#define D 128
#define KTOT 384
#define NPART 8

typedef unsigned short u16;
typedef short bf16x8 __attribute__((ext_vector_type(8)));
typedef float f32x4 __attribute__((ext_vector_type(4)));
typedef float f32x2 __attribute__((ext_vector_type(2)));

__device__ __forceinline__ u16 f2bf(float f) {
    unsigned u = __float_as_uint(f);
    unsigned r = (u + 0x7FFF + ((u >> 16) & 1)) >> 16;   // RNE
    return (u16)r;
}

// ---------------- weight prep: Wt[n][kt] = W_seg[k][n] (bf16), bias fold ----
__global__ __launch_bounds__(256) void prep_w_k(const float* __restrict__ W0,
                                                const float* __restrict__ W1,
                                                const float* __restrict__ W2,
                                                const float* __restrict__ b0,
                                                const float* __restrict__ b1,
                                                const float* __restrict__ b2,
                                                u16* __restrict__ Wt,
                                                float* __restrict__ biasc) {
    int idx = blockIdx.x * 256 + threadIdx.x;   // 128*384 = 49152
    if (idx < 128 * KTOT) {
        int n = idx / KTOT;          // 0..127
        int kt = idx - n * KTOT;     // 0..383
        int seg = kt >> 7;
        int k = kt & 127;
        const float* W = (seg == 0) ? W0 : (seg == 1) ? W1 : W2;
        Wt[n * KTOT + kt] = f2bf(W[k * D + n]);
    }
    if (idx < D) {
        biasc[idx] = b0[idx] + 0.5f * (b1[idx] + b2[idx]);
    }
}

// ---------------- x -> bf16 seg0 of Ab, and fp8 copy xq ----------------
__global__ __launch_bounds__(256) void conv_x_k(const float* __restrict__ x,
                                                u16* __restrict__ Ab,
                                                unsigned* __restrict__ xq,  // N*32 words
                                                int N) {
    int gid = blockIdx.x * 256 + threadIdx.x;
    int node = gid >> 5;
    int c = gid & 31;
    if (node >= N) return;
    float4 v = *(const float4*)&x[(size_t)node * D + c * 4];
    ushort4 o;
    o.x = f2bf(v.x); o.y = f2bf(v.y); o.z = f2bf(v.z); o.w = f2bf(v.w);
    *(ushort4*)&Ab[(size_t)node * KTOT + c * 4] = o;
    // pack 4 fp8 (e4m3, RNE) into one dword
    int q = __builtin_amdgcn_cvt_pk_fp8_f32(v.x, v.y, 0, false);
    q = __builtin_amdgcn_cvt_pk_fp8_f32(v.z, v.w, q, true);
    xq[(size_t)node * 32 + c] = (unsigned)q;
}

// ---------------- degrees over combined 2N space ----------------
// deg[d] (in-degree), deg[N+s] (out-degree). nt loads: edge stream must not
// evict the deg counter lines from L2.
__global__ __launch_bounds__(256) void deg_k(const int* __restrict__ ei, int E, int N,
                                             int* __restrict__ deg) {
    int e = blockIdx.x * 256 + threadIdx.x;
    if (e >= E) return;
    int s = __builtin_nontemporal_load(&ei[e]);
    int d = __builtin_nontemporal_load(&ei[E + e]);
    atomicAdd(&deg[d], 1);
    atomicAdd(&deg[N + s], 1);
}

// ---------------- block scan for CSR ptr ----------------
__device__ __forceinline__ int block_incl_scan(int v, int* wsum) {
    int lane = threadIdx.x & 63;
    int wv = threadIdx.x >> 6;
#pragma unroll
    for (int off = 1; off < 64; off <<= 1) {
        int t = __shfl_up(v, off, 64);
        if (lane >= off) v += t;
    }
    if (lane == 63) wsum[wv] = v;
    __syncthreads();
    int add = 0;
    for (int w = 0; w < wv; ++w) add += wsum[w];
    return v + add;
}

__global__ __launch_bounds__(256) void scan1_k(const int* __restrict__ in, int n,
                                               int* __restrict__ bsum) {
    __shared__ int wsum[4];
    int i = blockIdx.x * 256 + threadIdx.x;
    int v = (i < n) ? in[i] : 0;
    int s = block_incl_scan(v, wsum);
    if (threadIdx.x == 255) bsum[blockIdx.x] = s;
}

__global__ __launch_bounds__(1024) void scan2_k(int* __restrict__ bsum, int nb) {
    __shared__ int wsum[16];
    int i = threadIdx.x;
    int v = (i < nb) ? bsum[i] : 0;
    int s = block_incl_scan(v, wsum);
    if (i < nb) bsum[i] = s - v;
}

// also writes cur (fill cursor init) — drops a d2d memcpy launch
__global__ __launch_bounds__(256) void scan3_k(const int* __restrict__ in, int n,
                                               const int* __restrict__ bsum,
                                               int* __restrict__ ptr,
                                               int* __restrict__ cur) {
    __shared__ int wsum[4];
    int i = blockIdx.x * 256 + threadIdx.x;
    int v = (i < n) ? in[i] : 0;
    int s = block_incl_scan(v, wsum);
    int off = bsum[blockIdx.x];
    if (i < n) {
        int ex = off + s - v;
        ptr[i] = ex;
        cur[i] = ex;
    }
    if (i == n - 1) ptr[n] = off + s;
}

// ---------------- CSR fill over combined space, XCD-partitioned -------------
// blockIdx%8 = partition of [0,2N), blockIdx/8 = edge chunk. A partition only
// writes adj entries for its node range -> adj lines stay XCD-local. Edge
// reads are non-temporal so they don't evict the adj write-lines from L2.
__global__ __launch_bounds__(256) void fill_part_k(const int* __restrict__ ei, int E,
                                                   int pdiv, int N,
                                                   int* __restrict__ cur,
                                                   int* __restrict__ adj) {
    const int part = blockIdx.x & (NPART - 1);
    const int chunk = blockIdx.x >> 3;
    const int nchunk = gridDim.x >> 3;
    const int lo = part * pdiv;
    const int hi = min(2 * N, lo + pdiv);
    const long long per = ((long long)E + nchunk - 1) / nchunk;
    const int beg = (int)((long long)chunk * per);
    const int end = (int)min((long long)E, (long long)(chunk + 1) * per);
    for (int e = beg + threadIdx.x; e < end; e += 256) {
        int s = __builtin_nontemporal_load(&ei[e]);
        int d = __builtin_nontemporal_load(&ei[E + e]);
        if (d >= lo && d < hi) adj[atomicAdd(&cur[d], 1)] = s;          // in
        int os = N + s;
        if (os >= lo && os < hi) adj[atomicAdd(&cur[os], 1)] = d;       // out
    }
}

// ---------------- gather-mean: fp8 gather, bf16 output ----------------
// 32 threads per (node,dir). lane = tid&31; h = lane>>4 picks one of two
// neighbors per iteration; c8 = lane&15 -> 8 features (8 fp8 = uint2 load).
// adj/ptr reads non-temporal (one-pass) so xq gather lines stay cached.
// Writes 0.5*mean as bf16 into Ab[node][128 + dir*128 ...].
__global__ __launch_bounds__(256) void agg_k(const unsigned* __restrict__ xq,
                                             u16* __restrict__ Ab,
                                             const int* __restrict__ ptr,
                                             const int* __restrict__ adj,
                                             int N) {
    int gid = blockIdx.x * 256 + threadIdx.x;
    int node = gid >> 5;
    int lane = gid & 31;
    if (node >= N) return;
    const int dir = blockIdx.y;
    const int ci = dir * N + node;           // combined index
    const int h = lane >> 4;                 // 0/1: neighbor parity
    const int c8 = lane & 15;                // feature octet

    int beg = ptr[ci], end = ptr[ci + 1];
    float acc[8];
#pragma unroll
    for (int j = 0; j < 8; ++j) acc[j] = 0.f;

    for (int j0 = beg; j0 < end; j0 += 32) {
        int a = (j0 + lane < end) ? __builtin_nontemporal_load(&adj[j0 + lane]) : 0;
        int m = min(32, end - j0);
        for (int t = 0; t < m; t += 2) {
            int my = t + h;
            int nbr = __shfl(a, (my < m) ? my : 0, 32);
            if (my < m) {
                uint2 q = *(const uint2*)((const char*)xq + ((size_t)nbr * 128 + c8 * 8));
                f32x2 p0 = __builtin_amdgcn_cvt_pk_f32_fp8((int)q.x, false);
                f32x2 p1 = __builtin_amdgcn_cvt_pk_f32_fp8((int)q.x, true);
                f32x2 p2 = __builtin_amdgcn_cvt_pk_f32_fp8((int)q.y, false);
                f32x2 p3 = __builtin_amdgcn_cvt_pk_f32_fp8((int)q.y, true);
                acc[0] += p0.x; acc[1] += p0.y; acc[2] += p1.x; acc[3] += p1.y;
                acc[4] += p2.x; acc[5] += p2.y; acc[6] += p3.x; acc[7] += p3.y;
            }
        }
    }
    // combine the two neighbor-parity halves (lane ^ 16)
#pragma unroll
    for (int j = 0; j < 8; ++j) acc[j] += __shfl_xor(acc[j], 16, 32);

    if (h == 0) {
        float s = 0.5f / fmaxf((float)(end - beg), 1.0f);
        uint4 o;
        o.x = (unsigned)f2bf(acc[0] * s) | ((unsigned)f2bf(acc[1] * s) << 16);
        o.y = (unsigned)f2bf(acc[2] * s) | ((unsigned)f2bf(acc[3] * s) << 16);
        o.z = (unsigned)f2bf(acc[4] * s) | ((unsigned)f2bf(acc[5] * s) << 16);
        o.w = (unsigned)f2bf(acc[6] * s) | ((unsigned)f2bf(acc[7] * s) << 16);
        *(uint4*)&Ab[(size_t)node * KTOT + 128 + dir * 128 + c8 * 8] = o;
    }
}

// ---------------- MFMA GEMM: out[N][128] = Ab[N][384] @ Wt[128][384]^T ------
#define BK 64
__global__ __launch_bounds__(256) void gemm_k(const u16* __restrict__ Ab,
                                              const u16* __restrict__ Wt,
                                              const float* __restrict__ biasc,
                                              float* __restrict__ out, int N) {
    __shared__ u16 As[64 * 72];    // 64 rows x 64 k (+8 pad)
    __shared__ u16 Bs[128 * 72];   // 128 n-rows x 64 k (+8 pad)

    const int tid = threadIdx.x;
    const int row0 = blockIdx.x * 64;
    const int w = tid >> 6;        // wave 0..3
    const int lane = tid & 63;
    const int m = lane & 15;
    const int quad = lane >> 4;

    f32x4 acc[8];
#pragma unroll
    for (int t = 0; t < 8; ++t) acc[t] = (f32x4){0.f, 0.f, 0.f, 0.f};

    for (int kb = 0; kb < KTOT / BK; ++kb) {
        const int k0 = kb * BK;
        __syncthreads();
#pragma unroll
        for (int i = 0; i < 2; ++i) {
            int f = tid + i * 256;
            int r = f >> 3;
            int q8 = f & 7;
            int grow = row0 + r;
            uint4 v = make_uint4(0u, 0u, 0u, 0u);
            if (grow < N)
                v = *(const uint4*)&Ab[(size_t)grow * KTOT + k0 + q8 * 8];
            *(uint4*)&As[r * 72 + q8 * 8] = v;
        }
#pragma unroll
        for (int i = 0; i < 4; ++i) {
            int f = tid + i * 256;
            int n = f >> 3;
            int q8 = f & 7;
            uint4 v = *(const uint4*)&Wt[(size_t)n * KTOT + k0 + q8 * 8];
            *(uint4*)&Bs[n * 72 + q8 * 8] = v;
        }
        __syncthreads();

        bf16x8 a[2];
#pragma unroll
        for (int s = 0; s < 2; ++s)
            a[s] = *(const bf16x8*)&As[(w * 16 + m) * 72 + s * 32 + quad * 8];
#pragma unroll
        for (int t = 0; t < 8; ++t) {
#pragma unroll
            for (int s = 0; s < 2; ++s) {
                bf16x8 b = *(const bf16x8*)&Bs[(t * 16 + m) * 72 + s * 32 + quad * 8];
                acc[t] = __builtin_amdgcn_mfma_f32_16x16x32_bf16(a[s], b, acc[t], 0, 0, 0);
            }
        }
    }

    const int rowbase = row0 + w * 16 + quad * 4;
#pragma unroll
    for (int t = 0; t < 8; ++t) {
        int col = t * 16 + m;
        float b = biasc[col];
#pragma unroll
        for (int r = 0; r < 4; ++r) {
            int row = rowbase + r;
            if (row < N) out[(size_t)row * D + col] = acc[t][r] + b;
        }
    }
}

// ---------------------------------------------------------------------------

extern "C" void kernel_launch(void* const* d_in, const int* in_sizes, int n_in,
                              void* d_out, int out_size, void* d_ws, size_t ws_size,
                              hipStream_t stream) {
    const float* x      = (const float*)d_in[0];
    const float* W_self = (const float*)d_in[1];
    const float* b_self = (const float*)d_in[2];
    const float* W_s2d  = (const float*)d_in[3];
    const float* b_s2d  = (const float*)d_in[4];
    const float* W_d2s  = (const float*)d_in[5];
    const float* b_d2s  = (const float*)d_in[6];
    const int*   ei     = (const int*)d_in[7];

    const int N = in_sizes[0] / D;
    const int E = in_sizes[7] / 2;
    float* out = (float*)d_out;
    char* ws = (char*)d_ws;

    // ---- workspace layout (~99 MB) ----
    size_t o = 0;
    u16* Ab = (u16*)(ws + o);        o += (size_t)N * KTOT * sizeof(u16);
    unsigned* xq = (unsigned*)(ws + o); o += (size_t)N * 32 * sizeof(unsigned);
    u16* Wt = (u16*)(ws + o);        o += (size_t)D * KTOT * sizeof(u16);
    float* biasc = (float*)(ws + o); o += D * sizeof(float);
    int* deg = (int*)(ws + o);       o += (size_t)2 * N * sizeof(int);
    int* ptr = (int*)(ws + o);       o += ((size_t)2 * N + 1) * sizeof(int);
    int* cur = (int*)(ws + o);       o += (size_t)2 * N * sizeof(int);
    int* adj = (int*)(ws + o);       o += (size_t)2 * E * sizeof(int);
    int* bs  = (int*)(ws + o);       o += 1024 * sizeof(int);

    const int n2 = 2 * N;
    const int nb2 = (n2 + 255) / 256;               // 782 <= 1024
    const int edge_blocks = (E + 255) / 256;
    const int node32_blocks = (int)(((size_t)N * 32 + 255) / 256);
    const int gemm_blocks = (N + 63) / 64;
    const int pdiv = (n2 + NPART - 1) / NPART;      // 25000
    const int part_grid = NPART * 120;

    // prep: weights/bias, x conversion (bf16 + fp8), degrees
    hipMemsetAsync(deg, 0, (size_t)n2 * sizeof(int), stream);
    prep_w_k<<<(128 * KTOT + 255) / 256, 256, 0, stream>>>(W_self, W_s2d, W_d2s,
                                                           b_self, b_s2d, b_d2s,
                                                           Wt, biasc);
    conv_x_k<<<node32_blocks, 256, 0, stream>>>(x, Ab, xq, N);
    deg_k<<<edge_blocks, 256, 0, stream>>>(ei, E, N, deg);

    // combined CSR (one scan chain over 2N); scan3 also seeds cur
    scan1_k<<<nb2, 256, 0, stream>>>(deg, n2, bs);
    scan2_k<<<1, 1024, 0, stream>>>(bs, nb2);
    scan3_k<<<nb2, 256, 0, stream>>>(deg, n2, bs, ptr, cur);
    fill_part_k<<<part_grid, 256, 0, stream>>>(ei, E, pdiv, N, cur, adj);

    // aggregation (both dirs), fp8 gather
    dim3 agrid(node32_blocks, 2);
    agg_k<<<agrid, 256, 0, stream>>>(xq, Ab, ptr, adj, N);

    // fused MFMA GEMM
    gemm_k<<<gemm_blocks, 256, 0, stream>>>(Ab, Wt, biasc, out, N);
}